// Round 2
// baseline (88.885 us; speedup 1.0000x reference)
//
#include <hip/hip_runtime.h>

// y[b,o] = -sum_k |x[b,k] - W[o,k]| + bias[o]
// BATCH=1024, IN_F=512, OUT_F=512, fp32. Pure-VALU kernel (no MFMA possible).
//
// Design: lane = batch, o-loop is wave-uniform so W[o,k] comes in through the
// SMEM pipe as SGPRs (s_load) and feeds v_sub_f32 directly (1 SGPR operand
// allowed). x slice lives in VGPRs. Inner loop has ZERO LDS / vector-mem ops:
// 2 VALU per (b,o,k) element = the 6.8us chip floor at 2 waves/SIMD.
// Block = 64 batches x 32 outputs; 8 waves own k-chunks of 64; LDS tree
// reduce (all access patterns <=2-way bank aliasing = free) + epilogue.

#define BATCH 1024
#define IN_F  512
#define OUT_F 512

#define BB 64   // batches per block (= lanes of a wave)
#define BO 32   // outputs per block
#define KC 64   // k-elements per wave
#define NW 8    // waves per block = IN_F/KC

__global__ __launch_bounds__(512, 2)
void l1dist_kernel(const float* __restrict__ x,
                   const float* __restrict__ w,
                   const float* __restrict__ bias,
                   float* __restrict__ out)
{
    __shared__ float part[NW][BO][BB];    // 64 KB partials
    __shared__ float red[BO][BB + 1];     // +1 pad: conflict-free store-phase reads

    const int t    = threadIdx.x;
    const int lane = t & 63;
    const int wv   = __builtin_amdgcn_readfirstlane(t >> 6);  // force SGPR wave id
    const int o0   = blockIdx.x * BO;
    const int b0   = blockIdx.y * BB;
    const int k0   = wv * KC;

    // ---- preamble: this wave's x slice into VGPRs: xr[j] = x[b0+lane][k0+j]
    // (strided across lanes, but L1 absorbs the within-line re-reads; 32KB/wave)
    float xr[KC];
    const float* xp = x + (size_t)(b0 + lane) * IN_F + k0;
    #pragma unroll
    for (int j = 0; j < KC; j += 4) {
        float4 v = *(const float4*)(xp + j);
        xr[j + 0] = v.x; xr[j + 1] = v.y; xr[j + 2] = v.z; xr[j + 3] = v.w;
    }

    // ---- main loop: o is wave-uniform -> wrow[k] scalarizes to s_load.
    // 4 independent accumulator chains cover v_add latency (4cyc vs 2cyc issue).
    #pragma unroll 1
    for (int o = 0; o < BO; ++o) {
        const float* wrow = w + (size_t)(o0 + o) * IN_F + k0;
        float a0 = 0.f, a1 = 0.f, a2 = 0.f, a3 = 0.f;
        #pragma unroll
        for (int k = 0; k < KC; k += 4) {
            a0 += fabsf(xr[k + 0] - wrow[k + 0]);
            a1 += fabsf(xr[k + 1] - wrow[k + 1]);
            a2 += fabsf(xr[k + 2] - wrow[k + 2]);
            a3 += fabsf(xr[k + 3] - wrow[k + 3]);
        }
        part[wv][o][lane] = (a0 + a1) + (a2 + a3);  // lanes consecutive: 2-way, free
    }
    __syncthreads();

    // ---- reduce the 8 k-chunk partials; t -> (b = t&63, o = t>>6 + 8*i)
    // reads part[ww][o][b]: lanes sweep b -> 2-way aliasing only
    {
        const int b  = t & 63;
        const int oq = t >> 6;   // 0..7
        float s[4];
        #pragma unroll
        for (int i = 0; i < 4; ++i) {
            const int o = oq + 8 * i;
            float acc = 0.f;
            #pragma unroll
            for (int ww = 0; ww < NW; ++ww) acc += part[ww][o][b];
            s[i] = acc;
        }
        #pragma unroll
        for (int i = 0; i < 4; ++i) red[oq + 8 * i][b] = s[i];
    }
    __syncthreads();

    // ---- store: t -> (o = t&31, b = (t>>5)*4 + j); red read is conflict-free
    // via the +1 pad ((o*65+b)%32 distinct across lanes); global store coalesced
    // in 128B segments.
    {
        const int o  = t & 31;
        const int br = t >> 5;   // 0..15
        const float bs = bias[o0 + o];
        #pragma unroll
        for (int j = 0; j < 4; ++j) {
            const int b = br * 4 + j;
            out[(size_t)(b0 + b) * OUT_F + o0 + o] = bs - red[o][b];
        }
    }
}

extern "C" void kernel_launch(void* const* d_in, const int* in_sizes, int n_in,
                              void* d_out, int out_size, void* d_ws, size_t ws_size,
                              hipStream_t stream) {
    const float* x    = (const float*)d_in[0];
    const float* wgt  = (const float*)d_in[1];
    const float* bias = (const float*)d_in[2];
    float* out = (float*)d_out;

    dim3 grid(OUT_F / BO, BATCH / BB);  // (16,16) = 256 blocks -> 1 block/CU
    dim3 block(BB * NW);                // 512 threads = 8 waves
    l1dist_kernel<<<grid, block, 0, stream>>>(x, wgt, bias, out);
}

// Round 3
// 86.513 us; speedup vs baseline: 1.0274x; 1.0274x over previous
//
#include <hip/hip_runtime.h>

// y[b,o] = -sum_k |x[b,k] - W[o,k]| + bias[o]
// BATCH=1024, IN_F=512, OUT_F=512, fp32. Pure-VALU kernel (no MFMA possible).
//
// lane = batch; o-loop wave-uniform so W[o,k] scalarizes to s_load -> SGPRs
// feeding v_sub_f32 directly (verified R2: SGPR_Count=112). Inner loop has
// zero LDS / vector-mem ops.
//
// R2 lesson: grid=256 gave 1 block/CU (2 waves/SIMD, VALUBusy 28%) -> SMEM
// latency per o-iter exposed. This round: BO=16 -> grid=512 -> 2 blocks/CU,
// 4 waves/SIMD; LDS 36KB/block so both co-reside. VGPR=72 <= 128 ok.

#define BATCH 1024
#define IN_F  512
#define OUT_F 512

#define BB 64   // batches per block (= lanes of a wave)
#define BO 16   // outputs per block
#define KC 64   // k-elements per wave
#define NW 8    // waves per block = IN_F/KC

__global__ __launch_bounds__(512, 4)
void l1dist_kernel(const float* __restrict__ x,
                   const float* __restrict__ w,
                   const float* __restrict__ bias,
                   float* __restrict__ out)
{
    __shared__ float part[NW][BO][BB];    // 32 KB partials
    __shared__ float red[BO][BB + 1];     // 4.2 KB

    const int t    = threadIdx.x;
    const int lane = t & 63;
    const int wv   = __builtin_amdgcn_readfirstlane(t >> 6);  // SGPR wave id
    const int o0   = blockIdx.x * BO;
    const int b0   = blockIdx.y * BB;
    const int k0   = wv * KC;

    // ---- preamble: this wave's x slice into VGPRs: xr[j] = x[b0+lane][k0+j]
    float xr[KC];
    const float* xp = x + (size_t)(b0 + lane) * IN_F + k0;
    #pragma unroll
    for (int j = 0; j < KC; j += 4) {
        float4 v = *(const float4*)(xp + j);
        xr[j + 0] = v.x; xr[j + 1] = v.y; xr[j + 2] = v.z; xr[j + 3] = v.w;
    }

    // ---- main loop: W via SMEM (SGPRs); 4 independent acc chains.
    #pragma unroll 1
    for (int o = 0; o < BO; ++o) {
        const float* wrow = w + (size_t)(o0 + o) * IN_F + k0;
        float a0 = 0.f, a1 = 0.f, a2 = 0.f, a3 = 0.f;
        #pragma unroll
        for (int k = 0; k < KC; k += 4) {
            a0 += fabsf(xr[k + 0] - wrow[k + 0]);
            a1 += fabsf(xr[k + 1] - wrow[k + 1]);
            a2 += fabsf(xr[k + 2] - wrow[k + 2]);
            a3 += fabsf(xr[k + 3] - wrow[k + 3]);
        }
        part[wv][o][lane] = (a0 + a1) + (a2 + a3);  // lanes sweep b: 2-way, free
    }
    __syncthreads();

    // ---- reduce 8 k-chunk partials; lanes sweep b -> 2-way aliasing only
    {
        const int b  = t & 63;
        const int oq = t >> 6;   // 0..7
        #pragma unroll
        for (int i = 0; i < 2; ++i) {
            const int o = oq + 8 * i;
            float acc = 0.f;
            #pragma unroll
            for (int ww = 0; ww < NW; ++ww) acc += part[ww][o][b];
            red[o][b] = acc;
        }
    }
    __syncthreads();

    // ---- store: t -> (o = t&15, b = t>>4), 2 b-values per thread
    {
        const int o  = t & 15;
        const int br = t >> 4;   // 0..31
        const float bs = bias[o0 + o];
        #pragma unroll
        for (int j = 0; j < 2; ++j) {
            const int b = br + 32 * j;
            out[(size_t)(b0 + b) * OUT_F + o0 + o] = bs - red[o][b];
        }
    }
}

extern "C" void kernel_launch(void* const* d_in, const int* in_sizes, int n_in,
                              void* d_out, int out_size, void* d_ws, size_t ws_size,
                              hipStream_t stream) {
    const float* x    = (const float*)d_in[0];
    const float* wgt  = (const float*)d_in[1];
    const float* bias = (const float*)d_in[2];
    float* out = (float*)d_out;

    dim3 grid(OUT_F / BO, BATCH / BB);  // (32,16) = 512 blocks -> 2 blocks/CU
    dim3 block(BB * NW);                // 512 threads = 8 waves
    l1dist_kernel<<<grid, block, 0, stream>>>(x, wgt, bias, out);
}

// Round 4
// 80.367 us; speedup vs baseline: 1.1060x; 1.0765x over previous
//
#include <hip/hip_runtime.h>

// y[b,o] = -sum_k |x[b,k] - W[o,k]| + bias[o]
// BATCH=1024, IN_F=512, OUT_F=512, fp32. Pure-VALU (no MFMA form exists).
//
// R2/R3 lesson: lane=b with W broadcast via SMEM stalls on scalar-cache
// misses every o-iter (VALUBusy 28%, occupancy-insensitive). LDS broadcast
// is pipe-bound. So: put K in the lanes -> ALL operands live in VGPRs, W
// loads are lane-varying coalesced dwordx4 (cannot scalarize), reused
// across 8 b's. Cross-lane k-sum = 4 shfl_xor steps amortized over 512 k.
//
// Layout: lane = bsub(2b) x slot(4b). Lane holds k in {jj*64 + slot*4 + c}
// for jj=0..7, c=0..3 -> per-jj float4 loads are 256B-contiguous per row16.
// Wave: 8 b (2 reg x 4 lane) x 16 o x 512 k. Block: 4 waves = 8 b x 64 o.
// Grid (128, 8) = 1024 blocks = 4/CU at 4 waves/SIMD. No LDS, no barriers.

#define BATCH 1024
#define IN_F  512
#define OUT_F 512

__global__ __launch_bounds__(256, 4)
void l1dist_kernel(const float* __restrict__ x,
                   const float* __restrict__ w,
                   const float* __restrict__ bias,
                   float* __restrict__ out)
{
    const int t    = threadIdx.x;
    const int lane = t & 63;
    const int wv   = t >> 6;        // 0..3: this wave's o-group
    const int slot = lane & 15;     // k-slot, also the kept-o index
    const int bsub = lane >> 4;     // 0..3
    const int b0   = blockIdx.x * 8;
    const int o0   = blockIdx.y * 64 + wv * 16;

    // ---- preload x into VGPRs: xr[breg][jj] = x[b][jj*64 + slot*4 ..+3]
    float4 xr[2][8];
    #pragma unroll
    for (int breg = 0; breg < 2; ++breg) {
        const float* xrow = x + (size_t)(b0 + breg * 4 + bsub) * IN_F + slot * 4;
        #pragma unroll
        for (int jj = 0; jj < 8; ++jj)
            xr[breg][jj] = *(const float4*)(xrow + jj * 64);
    }

    float keep0 = 0.f, keep1 = 0.f;

    #pragma unroll 1
    for (int ol = 0; ol < 16; ++ol) {
        // W row for this o: 8 coalesced dwordx4 (lane-varying, stays VMEM),
        // reused across all 8 b's below.
        const float* wrow = w + (size_t)(o0 + ol) * IN_F + slot * 4;
        float4 wr[8];
        #pragma unroll
        for (int jj = 0; jj < 8; ++jj)
            wr[jj] = *(const float4*)(wrow + jj * 64);

        float a00 = 0.f, a01 = 0.f, a10 = 0.f, a11 = 0.f;  // 2 chains x 2 breg
        #pragma unroll
        for (int jj = 0; jj < 8; ++jj) {
            a00 += fabsf(xr[0][jj].x - wr[jj].x);
            a01 += fabsf(xr[0][jj].y - wr[jj].y);
            a00 += fabsf(xr[0][jj].z - wr[jj].z);
            a01 += fabsf(xr[0][jj].w - wr[jj].w);
            a10 += fabsf(xr[1][jj].x - wr[jj].x);
            a11 += fabsf(xr[1][jj].y - wr[jj].y);
            a10 += fabsf(xr[1][jj].z - wr[jj].z);
            a11 += fabsf(xr[1][jj].w - wr[jj].w);
        }
        float r0 = a00 + a01;
        float r1 = a10 + a11;

        // sum the 16 k-slots within the row-of-16 (masks 1,2,4,8 never
        // cross a 16-lane boundary). VALU+LDS-crossbar, ~5% of iter time.
        #pragma unroll
        for (int m = 1; m <= 8; m <<= 1) {
            r0 += __shfl_xor(r0, m, 64);
            r1 += __shfl_xor(r1, m, 64);
        }
        // lane keeps the o matching its slot -> wave ends holding one
        // result per lane position, stored without any LDS transpose.
        if (slot == ol) { keep0 = r0; keep1 = r1; }
    }

    const float bv = bias[o0 + slot];
    out[(size_t)(b0 + 0 + bsub) * OUT_F + o0 + slot] = bv - keep0;
    out[(size_t)(b0 + 4 + bsub) * OUT_F + o0 + slot] = bv - keep1;
}

extern "C" void kernel_launch(void* const* d_in, const int* in_sizes, int n_in,
                              void* d_out, int out_size, void* d_ws, size_t ws_size,
                              hipStream_t stream) {
    const float* x    = (const float*)d_in[0];
    const float* wgt  = (const float*)d_in[1];
    const float* bias = (const float*)d_in[2];
    float* out = (float*)d_out;

    dim3 grid(BATCH / 8, OUT_F / 64);  // (128, 8) = 1024 blocks
    dim3 block(256);
    l1dist_kernel<<<grid, block, 0, stream>>>(x, wgt, bias, out);
}

// Round 5
// 74.943 us; speedup vs baseline: 1.1860x; 1.0724x over previous
//
#include <hip/hip_runtime.h>

// y[b,o] = -sum_k |x[b,k] - W[o,k]| + bias[o]
// BATCH=1024, IN_F=512, OUT_F=512, fp32. Pure-VALU (no MFMA form exists).
//
// R4 lesson: VMEM return path is per-LANE bytes (~64B/cyc/CU), no dedup of
// replicated addresses across quarter-waves -> broadcast-style loads bind
// the kernel (implied ~20us of VMEM pipe). This round every global load is
// 64-lane UNIQUE: the wave's 64 lanes span a full 2KB row (k = h*256 +
// lane*4 + c). x rows (8 per wave) live in VGPRs -> each W row load is
// reused 8x. k-reduction = value-splitting butterfly (7 shfl + 3 xor steps
// per o), independent of the next o's compute so it software-pipelines.
//
// Wave: 8 b x 16 o x 512 k. Block: 4 waves (same b, 64 consecutive o).
// Grid (128, 8) = 1024 blocks = 4/CU = 4 waves/SIMD. VGPR ~110. No LDS.

#define BATCH 1024
#define IN_F  512
#define OUT_F 512

__global__ __launch_bounds__(256, 4)
void l1dist_kernel(const float* __restrict__ x,
                   const float* __restrict__ w,
                   const float* __restrict__ bias,
                   float* __restrict__ out)
{
    const int t    = threadIdx.x;
    const int lane = t & 63;
    const int wv   = t >> 6;                 // 0..3
    const int b0   = blockIdx.x * 8;
    const int o0   = blockIdx.y * 64 + wv * 16;

    // ---- preload x: xr[b][h] = x[b0+b][h*256 + lane*4 ..+3]  (1KB unique/instr)
    float4 xr[8][2];
    #pragma unroll
    for (int b = 0; b < 8; ++b) {
        const float* xrow = x + (size_t)(b0 + b) * IN_F + lane * 4;
        xr[b][0] = *(const float4*)(xrow);
        xr[b][1] = *(const float4*)(xrow + 256);
    }

    const float* wp = w + (size_t)o0 * IN_F + lane * 4;

    // software pipeline: wr = current o's row, prefetch next inside the loop
    float4 wr0 = *(const float4*)(wp);
    float4 wr1 = *(const float4*)(wp + 256);

    #pragma unroll 2
    for (int o = 0; o < 16; ++o) {
        // prefetch next row (clamped: last iter redundantly reloads row 15)
        const int on = (o < 15) ? (o + 1) : 15;
        const float* npw = wp + (size_t)on * IN_F;
        const float4 nw0 = *(const float4*)(npw);
        const float4 nw1 = *(const float4*)(npw + 256);

        // ---- compute per-lane partials for 8 b's (pure VGPR VALU)
        float v[8];
        #pragma unroll
        for (int b = 0; b < 8; ++b) {
            float s0 = fabsf(xr[b][0].x - wr0.x) + fabsf(xr[b][0].y - wr0.y);
            s0      += fabsf(xr[b][0].z - wr0.z) + fabsf(xr[b][0].w - wr0.w);
            float s1 = fabsf(xr[b][1].x - wr1.x) + fabsf(xr[b][1].y - wr1.y);
            s1      += fabsf(xr[b][1].z - wr1.z) + fabsf(xr[b][1].w - wr1.w);
            v[b] = s0 + s1;
        }

        // ---- value-splitting butterfly: 8 values x 64 lanes -> each lane
        // holds the full 64-lane sum of b = brl(lane&7) after 6 xor levels.
        #pragma unroll
        for (int m = 1, n = 4; n >= 1; m <<= 1, n >>= 1) {
            const bool hi = (lane & m) != 0;
            #pragma unroll
            for (int i = 0; i < n; ++i) {
                const float send = hi ? v[i] : v[i + n];
                const float recv = __shfl_xor(send, m, 64);
                v[i] = (hi ? v[i + n] : v[i]) + recv;
            }
        }
        float r = v[0];
        r += __shfl_xor(r, 8, 64);
        r += __shfl_xor(r, 16, 64);
        r += __shfl_xor(r, 32, 64);

        // lane l<8 holds b = bitrev3(l): 4*(l&1) | (l&2) | ((l>>2)&1)
        if (lane < 8) {
            const int brl = ((lane & 1) << 2) | (lane & 2) | ((lane >> 2) & 1);
            out[(size_t)(b0 + brl) * OUT_F + o0 + o] = bias[o0 + o] - r;
        }

        wr0 = nw0;
        wr1 = nw1;
    }
}

extern "C" void kernel_launch(void* const* d_in, const int* in_sizes, int n_in,
                              void* d_out, int out_size, void* d_ws, size_t ws_size,
                              hipStream_t stream) {
    const float* x    = (const float*)d_in[0];
    const float* wgt  = (const float*)d_in[1];
    const float* bias = (const float*)d_in[2];
    float* out = (float*)d_out;

    dim3 grid(BATCH / 8, OUT_F / 64);  // (128, 8) = 1024 blocks
    dim3 block(256);                   // 4 waves
    l1dist_kernel<<<grid, block, 0, stream>>>(x, wgt, bias, out);
}

// Round 6
// 72.301 us; speedup vs baseline: 1.2294x; 1.0365x over previous
//
#include <hip/hip_runtime.h>

// y[b,o] = -sum_k |x[b,k] - W[o,k]| + bias[o]
// BATCH=1024, IN_F=512, OUT_F=512, fp32. Pure-VALU (no MFMA form exists).
//
// Structure (R5, verified): lane spans k (64 lanes x 8 k = 512), 8 x-rows
// in VGPRs, W row loaded once per o (64-lane-unique dwordx4) and reused 8x,
// value-splitting butterfly reduces 8 b-partials across the wave.
//
// R6 change: epilogue stores. R5 issued 16 stores/wave with 8 active lanes
// at 2KB stride (~128 line-transactions/wave -> ~5us of store-pipe). Now:
// per-o single ds_write_b32 into a per-wave LDS strip, then ONE readback +
// 2 fully-coalesced global stores (4x64B segments each). No barriers
// (same-wave LDS only). LDS 2KB/block.

#define BATCH 1024
#define IN_F  512
#define OUT_F 512

__global__ __launch_bounds__(256, 4)
void l1dist_kernel(const float* __restrict__ x,
                   const float* __restrict__ w,
                   const float* __restrict__ bias,
                   float* __restrict__ out)
{
    __shared__ float tmp[4][128];   // per-wave result strip: [wv][b*16+o]

    const int t    = threadIdx.x;
    const int lane = t & 63;
    const int wv   = t >> 6;                 // 0..3
    const int b0   = blockIdx.x * 8;
    const int o0   = blockIdx.y * 64 + wv * 16;

    // ---- preload x: xr[b][h] = x[b0+b][h*256 + lane*4 ..+3]  (1KB unique/instr)
    float4 xr[8][2];
    #pragma unroll
    for (int b = 0; b < 8; ++b) {
        const float* xrow = x + (size_t)(b0 + b) * IN_F + lane * 4;
        xr[b][0] = *(const float4*)(xrow);
        xr[b][1] = *(const float4*)(xrow + 256);
    }

    const float* wp = w + (size_t)o0 * IN_F + lane * 4;

    // software pipeline: wr = current o's row, prefetch next inside the loop
    float4 wr0 = *(const float4*)(wp);
    float4 wr1 = *(const float4*)(wp + 256);

    // lane l<8 ends the butterfly holding b = bitrev3(l)
    const int brl = ((lane & 1) << 2) | (lane & 2) | ((lane >> 2) & 1);

    #pragma unroll 2
    for (int o = 0; o < 16; ++o) {
        // prefetch next row (clamped: last iter redundantly reloads row 15)
        const int on = (o < 15) ? (o + 1) : 15;
        const float* npw = wp + (size_t)on * IN_F;
        const float4 nw0 = *(const float4*)(npw);
        const float4 nw1 = *(const float4*)(npw + 256);

        // ---- compute per-lane partials for 8 b's (pure VGPR VALU)
        float v[8];
        #pragma unroll
        for (int b = 0; b < 8; ++b) {
            float s0 = fabsf(xr[b][0].x - wr0.x) + fabsf(xr[b][0].y - wr0.y);
            s0      += fabsf(xr[b][0].z - wr0.z) + fabsf(xr[b][0].w - wr0.w);
            float s1 = fabsf(xr[b][1].x - wr1.x) + fabsf(xr[b][1].y - wr1.y);
            s1      += fabsf(xr[b][1].z - wr1.z) + fabsf(xr[b][1].w - wr1.w);
            v[b] = s0 + s1;
        }

        // ---- value-splitting butterfly: after 6 xor levels lane l<8 holds
        // the full 64-lane k-sum for b = bitrev3(l).
        #pragma unroll
        for (int m = 1, n = 4; n >= 1; m <<= 1, n >>= 1) {
            const bool hi = (lane & m) != 0;
            #pragma unroll
            for (int i = 0; i < n; ++i) {
                const float send = hi ? v[i] : v[i + n];
                const float recv = __shfl_xor(send, m, 64);
                v[i] = (hi ? v[i + n] : v[i]) + recv;
            }
        }
        float r = v[0];
        r += __shfl_xor(r, 8, 64);
        r += __shfl_xor(r, 16, 64);
        r += __shfl_xor(r, 32, 64);

        // park the result in this wave's LDS strip (1 tiny ds_write vs a
        // scattered 8-lane global store)
        if (lane < 8) tmp[wv][brl * 16 + o] = r;

        wr0 = nw0;
        wr1 = nw1;
    }

    // ---- coalesced epilogue: 128 results/wave -> 2 wave-wide stores,
    // each 4 contiguous 64B segments. Same-wave LDS: no barrier needed.
    const float bv = bias[o0 + (lane & 15)];
    const float f0 = tmp[wv][lane];
    const float f1 = tmp[wv][64 + lane];
    out[(size_t)(b0 + (lane >> 4) + 0) * OUT_F + o0 + (lane & 15)] = bv - f0;
    out[(size_t)(b0 + (lane >> 4) + 4) * OUT_F + o0 + (lane & 15)] = bv - f1;
}

extern "C" void kernel_launch(void* const* d_in, const int* in_sizes, int n_in,
                              void* d_out, int out_size, void* d_ws, size_t ws_size,
                              hipStream_t stream) {
    const float* x    = (const float*)d_in[0];
    const float* wgt  = (const float*)d_in[1];
    const float* bias = (const float*)d_in[2];
    float* out = (float*)d_out;

    dim3 grid(BATCH / 8, OUT_F / 64);  // (128, 8) = 1024 blocks = 4/CU
    dim3 block(256);                   // 4 waves
    l1dist_kernel<<<grid, block, 0, stream>>>(x, wgt, bias, out);
}